// Round 4
// baseline (287.198 us; speedup 1.0000x reference)
//
#include <hip/hip_runtime.h>

// Problem constants (from reference)
#define B_   16
#define OC_  10
#define N_   256
#define O_   2560   // OC_*N_
#define S_   64     // synapses
#define T_   512
#define KS_  48
#define TP_  561    // T + KS + 1
#define TT   24     // (fallback conv) time steps per thread
#define WROW 72     // (fallback conv) LDS row stride

// B-stationary GEMM constants
#define NOC   160           // o-chunks of 16 outputs
#define XROWS 624           // xT rows: t' + 48 - j range, zero-padded

#define SCH    16           // neurons per scan block = one 64-B pot line
#define CPITCH 572          // scan LDS row pitch (143 dwords, gcd(143,32)=1)

using i32x4 = __attribute__((ext_vector_type(4))) int;

// ===========================================================================
// prep_all: one dispatch, grid-strided.
//  - blocks [0, 512):    x [16][64][512] f32 -> xb [16][512][64] {0,1}  (x4)
//  - blocks [512, 2432): taps -> three signed base-256 digits (22-bit fixed
//    point) into Bg[oc][pos][row=d*16+ol][64], pos = 3*jm + jh  (x16)
// ===========================================================================
__global__ void prep_all(const float* __restrict__ x, const float* __restrict__ w,
                         unsigned char* __restrict__ xb, signed char* __restrict__ Bg) {
    if (blockIdx.x < 512) {
#pragma unroll
        for (int it = 0; it < 4; ++it) {
            int idx = blockIdx.x * 256 + threadIdx.x + it * 131072;  // < 524288
            int t = idx & 511;
            int bi = idx >> 9;
            int i = bi & 63, b = bi >> 6;
            xb[((size_t)(b * 512 + t) << 6) + i] = (x[idx] != 0.0f) ? 1 : 0;
        }
    } else {
        int base = (blockIdx.x - 512) * 256 + threadIdx.x;
#pragma unroll
        for (int it = 0; it < 16; ++it) {
            int idx = base + it * 491520;                  // < 7,864,320 exactly
            int i = idx & 63;
            int oj = idx >> 6;
            int j = oj % KS_, o = oj / KS_;
            float wv = w[(o << 6) + i];
            float rise = (float)j * 0.0625f;
            float leak = -((float)j - wv * 16.0f) * 0.03125f + wv;
            float kv   = fmaxf(0.0f, fminf(rise, leak));     // in [0,1]
            int q  = (int)lrintf(kv * 4194304.0f);           // kv * 2^22
            int d0 = ((q + 128) & 255) - 128;                // [-128,127]
            int q1 = (q - d0) >> 8;
            int d1 = ((q1 + 128) & 255) - 128;               // [-128,127]
            int d2 = (q1 - d1) >> 8;                         // [0,64]
            int oc = o >> 4, ol = o & 15;
            int jm = j & 15, jh = j >> 4;
            int pos = jm * 3 + jh;                           // triple-grouped
            size_t bse = (((size_t)(oc * KS_ + pos) * 48) + ol) * 64 + i;
            Bg[bse]            = (signed char)d0;            // digit 0
            Bg[bse + 16 * 64]  = (signed char)d1;            // digit 1
            Bg[bse + 32 * 64]  = (signed char)d2;            // digit 2
        }
    }
}

// ===========================================================================
// gemm_i8 (r15): occupancy push — 6 waves x 6 m-tiles, 3 waves/SIMD.
// r13/r14 post-mortem: two pipelining variants both pinned at MfmaUtil ~74%
// with 2 waves/SIMD (216 unified regs/wave).  The i8 16x16 ubench reaches
// 79% at 8 waves/SIMD -> the residual is latency-hiding TLP, not schedule
// order.  This version buys a 3rd wave/SIMD:
//   - M per wave 144 -> 96 (6 tiles): acc 108 -> 72 AGPR
//   - af window 11 -> 8 frags (32 VGPR), reloaded at per-slot death points
//   - bf double-buffer -> IN-PLACE single buffer (36 VGPR): each jh-triple
//     reloads right after its last use (lead ~36 MFMAs >= L2 latency)
//   - __launch_bounds__(384, 3): cap 170 unified regs -> 12 waves/CU
// Barrier-free main loop, A in LDS (XOR-swizzled, conflict-free b128),
// B from global (L2/L1-resident), exact int32 accumulation.
// ===========================================================================
__global__ __launch_bounds__(384, 3) void gemm_i8(
    const unsigned char* __restrict__ xb,   // [16][512][64]
    const signed char*  __restrict__ Bg,    // [NOC][48][48][64] plain
    float* __restrict__ pot)                // [B_*TP_][O_]
{
    __shared__ __align__(16) unsigned char xT[XROWS * 64];     // 39,936 B

    const int tid  = threadIdx.x;
    const int lane = tid & 63;
    const int wave = tid >> 6;             // 0..5
    const int oc = blockIdx.x;             // 0..159
    const int b  = blockIdx.y;             // 0..15
    const int lrow = lane & 15;
    const int quad = lane >> 4;
    const int tw = wave * 96;              // wave m-base (t), 6 tiles of 16

    // per-lane base into this oc's Bg slice: row=lrow (output), bytes quad*16
    const signed char* Bgb = Bg + (size_t)oc * (KS_ * 48 * 64)
                           + lrow * 64 + quad * 16;

    // xT fill: zero ONLY pad rows (0..48, 561..623); data rows 49..560 <- x[b]
    for (int z = tid; z < 112 * 4; z += 384) {
        int zi = z >> 2, p = z & 3;
        int r = (zi < 49) ? zi : (561 + zi - 49);
        *(i32x4*)(xT + r * 64 + p * 16) = (i32x4){0, 0, 0, 0};
    }
    const unsigned char* xbb = xb + ((size_t)b << 15);   // 512*64 bytes
    for (int q = tid; q < 2048; q += 384) {              // 16-B chunks
        i32x4 v = *(const i32x4*)(xbb + q * 16);
        int t = q >> 2, p = q & 3;
        int r = 49 + t;
        *(i32x4*)(xT + r * 64 + ((p ^ ((r >> 1) & 3)) << 4)) = v;
    }

    i32x4 acc[6][3];
#pragma unroll
    for (int mi = 0; mi < 6; ++mi)
#pragma unroll
        for (int f = 0; f < 3; ++f)
            acc[mi][f] = (i32x4){0, 0, 0, 0};

    i32x4 af[8], bf[9];

    // B(t=0) prefetch issued before the barrier (global, no xT dependency)
#pragma unroll
    for (int jh = 0; jh < 3; ++jh)
#pragma unroll
        for (int f = 0; f < 3; ++f)
            bf[jh * 3 + f] = *(const i32x4*)(Bgb + jh * 3072 + f * 1024);

    __syncthreads();   // xT ready (only barrier in the kernel)

    // af prologue for t=0: af[k] = row tw+16+16k (+lrow)
    {
        const int rb0 = tw + 16 + lrow;
        const int ca0 = ((quad ^ ((rb0 >> 1) & 3)) << 4);
#pragma unroll
        for (int k = 0; k < 8; ++k)
            af[k] = *(const i32x4*)(xT + (rb0 + k * 16) * 64 + ca0);
    }

#define MF(mi, jh, f)                                                         \
    acc[mi][f] = __builtin_amdgcn_mfma_i32_16x16x64_i8(                       \
        af[(mi) + 2 - (jh)], bf[(jh) * 3 + (f)], acc[mi][f], 0, 0, 0)

#define LDA_(row) (*(const i32x4*)(xT + (row) * 64 + coffN))
#define LDB_(jh, f) (*(const i32x4*)(Bgb + (tn3 + (jh)) * 3072 + (f) * 1024))

#pragma unroll
    for (int t = 0; t < 16; ++t) {
        const int tn  = (t + 1) & 15;                 // next tloc (t=15 wraps, dummy)
        const int rbn = tw + 16 - tn + lrow;          // next-tloc base row
        const int coffN = ((quad ^ ((rbn >> 1) & 3)) << 4);
        const int tn3 = tn * 3;

        // ---- jh = 0: af[2..7], bf[0..2] ----
        __builtin_amdgcn_s_setprio(1);
        MF(0,0,0); MF(0,0,1); MF(0,0,2);  MF(1,0,0); MF(1,0,1); MF(1,0,2);
        MF(2,0,0); MF(2,0,1); MF(2,0,2);  MF(3,0,0); MF(3,0,1); MF(3,0,2);
        MF(4,0,0); MF(4,0,1); MF(4,0,2);  MF(5,0,0); MF(5,0,1); MF(5,0,2);
        __builtin_amdgcn_s_setprio(0);
        bf[0] = LDB_(0, 0); bf[1] = LDB_(0, 1); bf[2] = LDB_(0, 2);   // t+1 jh0

        // ---- jh = 1: af[1..6], bf[3..5]; af[7] free -> reload mid-cluster --
        __builtin_amdgcn_s_setprio(1);
        MF(0,1,0); MF(0,1,1); MF(0,1,2);  MF(1,1,0); MF(1,1,1); MF(1,1,2);
        MF(2,1,0); MF(2,1,1); MF(2,1,2);
        af[7] = LDA_(rbn + 112);
        MF(3,1,0); MF(3,1,1); MF(3,1,2);  MF(4,1,0); MF(4,1,1); MF(4,1,2);
        MF(5,1,0); MF(5,1,1); MF(5,1,2);
        __builtin_amdgcn_s_setprio(0);
        bf[3] = LDB_(1, 0); bf[4] = LDB_(1, 1); bf[5] = LDB_(1, 2);   // t+1 jh1

        // ---- jh = 2: af[0..5], bf[6..8]; per-mi af death -> reload in place
        __builtin_amdgcn_s_setprio(1);
        af[6] = LDA_(rbn + 96);                        // af[6] free after jh1
        MF(0,2,0); MF(0,2,1); MF(0,2,2);  af[0] = LDA_(rbn);
        MF(1,2,0); MF(1,2,1); MF(1,2,2);  af[1] = LDA_(rbn + 16);
        MF(2,2,0); MF(2,2,1); MF(2,2,2);  af[2] = LDA_(rbn + 32);
        MF(3,2,0); MF(3,2,1); MF(3,2,2);  af[3] = LDA_(rbn + 48);
        MF(4,2,0); MF(4,2,1); MF(4,2,2);  af[4] = LDA_(rbn + 64);
        MF(5,2,0); MF(5,2,1); MF(5,2,2);  af[5] = LDA_(rbn + 80);
        __builtin_amdgcn_s_setprio(0);
        bf[6] = LDB_(2, 0); bf[7] = LDB_(2, 1); bf[8] = LDB_(2, 2);   // t+1 jh2
    }

#undef MF
#undef LDA_
#undef LDB_

    // epilogue: C/D col=lane&15 (ol), row=quad*4+r (t); digits in-lane
    const size_t potb = (size_t)b * TP_;
#pragma unroll
    for (int mi = 0; mi < 6; ++mi) {
#pragma unroll
        for (int r = 0; r < 4; ++r) {
            int t = tw + mi * 16 + quad * 4 + r;
            if (t < TP_) {
                double pq = ((double)acc[mi][0][r]
                           + 256.0   * (double)acc[mi][1][r]
                           + 65536.0 * (double)acc[mi][2][r])
                          * (1.0 / 4194304.0);
                pot[(potb + t) * O_ + oc * 16 + lrow] = (float)pq;
            }
        }
    }
}

// ===========================================================================
// scan_fused: memset + scan_prep + scan_run in ONE kernel.
// block = (nc, b): SCH=16 neurons x 1024 threads.
//  P1: argmax/threshold from pot -> codeW[nl][t] in LDS (bit-identical
//      decisions to the reference scan).
//  P2: ballot-based depression walk — wave w owns neuron w; 64-lane window,
//      __ballot + ctz finds the first spike, uniform advance >= 48.
//      Decision-identical to the serial reference walk.
//  P3: all threads densely write the 10x16x561 output tile.
// ===========================================================================
__global__ __launch_bounds__(1024) void scan_fused(
    const float* __restrict__ pot,    // [B_*TP_][O_]
    float* __restrict__ out)          // [B_][OC_][N_][TP_]
{
    __shared__ unsigned char codeW[SCH * CPITCH];   // [nl][t]
    __shared__ unsigned char ocW[SCH * CPITCH];

    const int tid = threadIdx.x;
    const int nc = blockIdx.x;        // 0..15 (neuron chunk of 16)
    const int b  = blockIdx.y;        // 0..15
    const int n0 = nc * SCH;

    // P1: per (t, nl) argmax over 10 channels + threshold
    for (int pair = tid; pair < TP_ * SCH; pair += 1024) {
        int t = pair >> 4, nl = pair & 15;
        const float* p = pot + ((size_t)(b * TP_ + t)) * O_ + n0 + nl;
        float best = p[0]; int bo = 0;
#pragma unroll
        for (int ch = 1; ch < OC_; ++ch) {
            float v = p[ch * N_];
            if (v > best) { best = v; bo = ch; }   // strict >: FIRST max wins
        }
        codeW[nl * CPITCH + t] =
            ((best + 16.0f) > 32.0f) ? (unsigned char)(bo + 1) : (unsigned char)0;
        ocW[nl * CPITCH + t] = 0;
    }
    __syncthreads();

    // P2: ballot depression walk — wave w = neuron w, all 64 lanes scan
    {
        const int wv = tid >> 6;          // 0..15 == nl
        const int ln = tid & 63;
        const unsigned char* c = &codeW[wv * CPITCH];
        unsigned char* o = &ocW[wv * CPITCH];
        int t = 0;
        while (t < TP_) {
            int tt = t + ln;
            unsigned char v = (tt < TP_) ? c[tt] : (unsigned char)0;
            unsigned long long mask = __ballot(v != 0);
            if (mask == 0ULL) { t += 64; continue; }
            int k = (int)__builtin_ctzll(mask);
            if (ln == k) o[t + k] = v;    // lane k holds the winner code
            t += k + KS_;
        }
    }
    __syncthreads();

    // P3: dense output write: out[b][ch][n0+nl][t]
    float* ob = out + (((size_t)b * OC_) * N_ + n0) * TP_;
    for (int idx = tid; idx < OC_ * SCH * TP_; idx += 1024) {
        int r = idx / TP_;            // r = ch*16 + nl
        int t = idx - r * TP_;
        int ch = r >> 4, nl = r & 15;
        float v = (ocW[nl * CPITCH + t] == (unsigned char)(ch + 1)) ? 1.0f : 0.0f;
        ob[((size_t)ch * N_ + nl) * TP_ + t] = v;
    }
}

// ===========================================================================
// FALLBACK (round-1 direct conv) — only if ws_size too small
// ===========================================================================
__global__ void transpose_w(const float* __restrict__ w, float* __restrict__ wT) {
    int idx = blockIdx.x * 256 + threadIdx.x;
    if (idx >= O_ * S_) return;
    int o = idx >> 6, i = idx & 63;
    wT[i * O_ + o] = w[idx];
}

__global__ __launch_bounds__(256) void conv_kernel(
    const float* __restrict__ x, const float* __restrict__ wT,
    float* __restrict__ pot)
{
    const int b  = blockIdx.y;
    const int t0 = blockIdx.z * TT;
    const int o  = blockIdx.x * 256 + threadIdx.x;

    __shared__ __align__(16) float xsh[S_][WROW];
    for (int idx = threadIdx.x; idx < S_ * WROW; idx += 256) {
        int i = idx / WROW, m = idx - i * WROW;
        int t = t0 - KS_ + m;
        float v = 0.0f;
        if (t >= 0 && t < T_) v = x[(b * S_ + i) * T_ + t];
        xsh[i][m] = v;
    }
    __syncthreads();

    float acch[TT], accl[TT];
#pragma unroll
    for (int tl = 0; tl < TT; ++tl) { acch[tl] = 0.0f; accl[tl] = 0.0f; }

    for (int i = 0; i < S_; ++i) {
        float xw[WROW];
#pragma unroll
        for (int w4 = 0; w4 < WROW / 4; ++w4) {
            const float4 v = *reinterpret_cast<const float4*>(&xsh[i][w4 * 4]);
            xw[w4 * 4 + 0] = v.x; xw[w4 * 4 + 1] = v.y;
            xw[w4 * 4 + 2] = v.z; xw[w4 * 4 + 3] = v.w;
        }
        const float wv = wT[i * O_ + o];
#pragma unroll
        for (int j = 1; j < KS_; ++j) {
            float rise = (float)j * 0.0625f;
            float leak = -((float)j - wv * 16.0f) * 0.03125f + wv;
            float kv   = fmaxf(0.0f, fminf(rise, leak));
            float khi  = rintf(kv * 4096.0f) * 2.44140625e-4f;
            float klo  = kv - khi;
#pragma unroll
            for (int tl = 0; tl < TT; ++tl) {
                float xv = xw[tl + (KS_ - 1) - j];
                acch[tl] = fmaf(xv, khi, acch[tl]);
                accl[tl] = fmaf(xv, klo, accl[tl]);
            }
        }
    }
#pragma unroll
    for (int tl = 0; tl < TT; ++tl) {
        int t = t0 + tl;
        if (t < TP_) pot[((size_t)b * TP_ + t) * O_ + o] = acch[tl] + accl[tl];
    }
}

__global__ void scan_prep(const float* __restrict__ pot, unsigned char* __restrict__ code) {
    int idx = blockIdx.x * 256 + threadIdx.x;
    if (idx >= B_ * TP_ * N_) return;
    int n  = idx & (N_ - 1);
    int bt = idx >> 8;
    const float* p = pot + (size_t)bt * O_ + n;
    float best = p[0]; int bo = 0;
#pragma unroll
    for (int oc = 1; oc < OC_; ++oc) {
        float v = p[oc * N_];
        if (v > best) { best = v; bo = oc; }
    }
    code[idx] = ((best + 16.0f) > 32.0f) ? (unsigned char)(bo + 1) : (unsigned char)0;
}

__global__ void scan_run(const unsigned char* __restrict__ code, float* __restrict__ out) {
    int idx = blockIdx.x * 256 + threadIdx.x;
    if (idx >= B_ * N_) return;
    int b = idx >> 8, n = idx & 255;
    const unsigned char* c = code + (size_t)b * TP_ * N_ + n;
    int t = 0;
    while (t < TP_) {
        unsigned char buf[KS_];
#pragma unroll
        for (int k = 0; k < KS_; ++k) {
            int tt = t + k;
            buf[k] = (tt < TP_) ? c[(size_t)tt * N_] : (unsigned char)0;
        }
        int adv = KS_;
#pragma unroll
        for (int k = 0; k < KS_; ++k) {
            if (buf[k]) {
                out[(((size_t)b * OC_ + (buf[k] - 1)) * N_ + n) * TP_ + (t + k)] = 1.0f;
                adv = k + KS_;
                break;
            }
        }
        t += adv;
    }
}

// ===========================================================================
extern "C" void kernel_launch(void* const* d_in, const int* in_sizes, int n_in,
                              void* d_out, int out_size, void* d_ws, size_t ws_size,
                              hipStream_t stream) {
    const float* x = (const float*)d_in[0];   // [16][1][64][512] binary
    const float* w = (const float*)d_in[1];   // [2560][64]
    float* out = (float*)d_out;               // [16][10][256][561]

    char* ws = (char*)d_ws;
    const size_t szX = (size_t)B_ * T_ * S_;                    //     524,288
    const size_t szB = (size_t)NOC * KS_ * 48 * 64;             //  23,592,960
    const size_t szP = (size_t)B_ * TP_ * O_ * 4;               //  91,914,240
    const size_t szC = (size_t)B_ * TP_ * N_;                   //   2,297,856
    const size_t need = szX + szB + szP + szC;                  // ~118.3 MB

    if (ws_size >= need) {
        unsigned char* xb  = (unsigned char*)ws;
        signed char* Bg    = (signed char*)(ws + szX);
        float* pot         = (float*)(ws + szX + szB);

        prep_all<<<2432, 256, 0, stream>>>(x, w, xb, Bg);
        gemm_i8<<<dim3(NOC, B_), 384, 0, stream>>>(xb, Bg, pot);
        scan_fused<<<dim3(N_ / SCH, B_), 1024, 0, stream>>>(pot, out);
    } else {
        // fallback: round-1 direct conv (needs ~95 MB)
        size_t pot_bytes  = (size_t)B_ * TP_ * O_ * sizeof(float);
        size_t code_bytes = (size_t)B_ * TP_ * N_;
        float* pot = (float*)ws;
        unsigned char* code = (unsigned char*)(ws + pot_bytes);
        float* wT = (float*)(ws + pot_bytes + code_bytes);

        hipMemsetAsync(d_out, 0, (size_t)out_size * sizeof(float), stream);
        transpose_w<<<(O_ * S_ + 255) / 256, 256, 0, stream>>>(w, wT);
        conv_kernel<<<dim3(O_ / 256, B_, (TP_ + TT - 1) / TT), 256, 0, stream>>>(x, wT, pot);
        scan_prep<<<(B_ * TP_ * N_ + 255) / 256, 256, 0, stream>>>(pot, code);
        scan_run<<<(B_ * N_ + 255) / 256, 256, 0, stream>>>(code, out);
    }
}

// Round 6
// 245.041 us; speedup vs baseline: 1.1720x; 1.1720x over previous
//
#include <hip/hip_runtime.h>

// Problem constants (from reference)
#define B_   16
#define OC_  10
#define N_   256
#define O_   2560   // OC_*N_
#define S_   64     // synapses
#define T_   512
#define KS_  48
#define TP_  561    // T + KS + 1
#define TT   24     // (fallback conv) time steps per thread
#define WROW 72     // (fallback conv) LDS row stride

// B-stationary GEMM constants
#define NOC   160           // o-chunks of 16 outputs
#define XROWS 624           // xT rows: t' + 48 - j range, zero-padded

#define SCH    16           // neurons per scan block = one 64-B pot line
#define CPITCH 572          // scan LDS row pitch (143 dwords, gcd(143,32)=1)

using i32x4 = __attribute__((ext_vector_type(4))) int;

// ===========================================================================
// prep_all: one dispatch, grid-strided.
//  - blocks [0, 512):    x [16][64][512] f32 -> xb [16][512][64] {0,1}  (x4)
//  - blocks [512, 2432): taps -> three signed base-256 digits (22-bit fixed
//    point) into Bg[oc][pos][row=d*16+ol][64], pos = 3*jm + jh  (x16)
// ===========================================================================
__global__ void prep_all(const float* __restrict__ x, const float* __restrict__ w,
                         unsigned char* __restrict__ xb, signed char* __restrict__ Bg) {
    if (blockIdx.x < 512) {
#pragma unroll
        for (int it = 0; it < 4; ++it) {
            int idx = blockIdx.x * 256 + threadIdx.x + it * 131072;  // < 524288
            int t = idx & 511;
            int bi = idx >> 9;
            int i = bi & 63, b = bi >> 6;
            xb[((size_t)(b * 512 + t) << 6) + i] = (x[idx] != 0.0f) ? 1 : 0;
        }
    } else {
        int base = (blockIdx.x - 512) * 256 + threadIdx.x;
#pragma unroll
        for (int it = 0; it < 16; ++it) {
            int idx = base + it * 491520;                  // < 7,864,320 exactly
            int i = idx & 63;
            int oj = idx >> 6;
            int j = oj % KS_, o = oj / KS_;
            float wv = w[(o << 6) + i];
            float rise = (float)j * 0.0625f;
            float leak = -((float)j - wv * 16.0f) * 0.03125f + wv;
            float kv   = fmaxf(0.0f, fminf(rise, leak));     // in [0,1]
            int q  = (int)lrintf(kv * 4194304.0f);           // kv * 2^22
            int d0 = ((q + 128) & 255) - 128;                // [-128,127]
            int q1 = (q - d0) >> 8;
            int d1 = ((q1 + 128) & 255) - 128;               // [-128,127]
            int d2 = (q1 - d1) >> 8;                         // [0,64]
            int oc = o >> 4, ol = o & 15;
            int jm = j & 15, jh = j >> 4;
            int pos = jm * 3 + jh;                           // triple-grouped
            size_t bse = (((size_t)(oc * KS_ + pos) * 48) + ol) * 64 + i;
            Bg[bse]            = (signed char)d0;            // digit 0
            Bg[bse + 16 * 64]  = (signed char)d1;            // digit 1
            Bg[bse + 32 * 64]  = (signed char)d2;            // digit 2
        }
    }
}

// ===========================================================================
// gemm_i8 (r16 = r14 revert): intra-wave software pipeline, 4 waves x 144.
// r15 post-mortem: HW register quantum is coarse (steps at 64/128/256 unified
// regs) -> 152-reg waves still land in the 256-slot class -> 2 waves/SIMD,
// and 6-wave blocks then can't pack 2-per-CU (only 8 slots) -> occupancy
// DROPPED.  2 waves/SIMD is the ceiling for any tiling with >128 total regs;
// r14's 4-wave/256-thread blocks pack 8 slots exactly.  This is the proven
// 122.0 us / 74% MfmaUtil configuration (90% of the 3944-TOPS 16x16-i8
// ubench ceiling).
//  - A (x) in LDS: xT [624][64], 16-B chunk XOR swizzle, conflict-free b128.
//  - B from GLOBAL (L2-resident 147 KB/oc slice), coalesced 1 KB fragments.
//  - Barrier-free main loop; mi-outer MFMA order; af registers roll in place.
//  - mfma_i32_16x16x64_i8, exact int32 accumulation, in-lane digit combine.
// ===========================================================================
__global__ __launch_bounds__(256, 2) void gemm_i8(
    const unsigned char* __restrict__ xb,   // [16][512][64]
    const signed char*  __restrict__ Bg,    // [NOC][48][48][64] plain
    float* __restrict__ pot)                // [B_*TP_][O_]
{
    __shared__ __align__(16) unsigned char xT[XROWS * 64];     // 39,936 B

    const int tid  = threadIdx.x;
    const int lane = tid & 63;
    const int wave = tid >> 6;
    const int oc = blockIdx.x;             // 0..159
    const int b  = blockIdx.y;             // 0..15
    const int lrow = lane & 15;
    const int quad = lane >> 4;
    const int tw = wave * 144;             // wave m-base (t)

    // per-lane base into this oc's Bg slice: row=lrow (output), bytes quad*16
    const signed char* Bgb = Bg + (size_t)oc * (KS_ * 48 * 64)
                           + lrow * 64 + quad * 16;

    // xT fill: zero ONLY pad rows (0..48, 561..623); data rows 49..560 <- x[b]
    for (int z = tid; z < 112 * 4; z += 256) {
        int zi = z >> 2, p = z & 3;
        int r = (zi < 49) ? zi : (561 + zi - 49);
        *(i32x4*)(xT + r * 64 + p * 16) = (i32x4){0, 0, 0, 0};
    }
    const unsigned char* xbb = xb + ((size_t)b << 15);   // 512*64 bytes
    for (int q = tid; q < 2048; q += 256) {              // 16-B chunks
        i32x4 v = *(const i32x4*)(xbb + q * 16);
        int t = q >> 2, p = q & 3;
        int r = 49 + t;
        *(i32x4*)(xT + r * 64 + ((p ^ ((r >> 1) & 3)) << 4)) = v;
    }

    i32x4 acc[9][3];
#pragma unroll
    for (int mi = 0; mi < 9; ++mi)
#pragma unroll
        for (int f = 0; f < 3; ++f)
            acc[mi][f] = (i32x4){0, 0, 0, 0};

    i32x4 af[11], bfA[9], bfB[9];

    // B(t=0) prefetch issued before the barrier (global, no xT dependency)
#pragma unroll
    for (int jh = 0; jh < 3; ++jh)
#pragma unroll
        for (int f = 0; f < 3; ++f)
            bfA[jh * 3 + f] = *(const i32x4*)(Bgb + jh * 3072 + f * 1024);

    __syncthreads();   // xT ready (only barrier in the kernel)

    // af prologue for t=0
    {
        const int rb0 = tw + 16 + lrow;
        const int ca0 = ((quad ^ ((rb0 >> 1) & 3)) << 4);
#pragma unroll
        for (int k = 0; k < 11; ++k)
            af[k] = *(const i32x4*)(xT + (rb0 + k * 16) * 64 + ca0);
    }

#define MF(bfC, mi, jh, f)                                                    \
    acc[mi][f] = __builtin_amdgcn_mfma_i32_16x16x64_i8(                       \
        af[(mi) + 2 - (jh)], bfC[(jh) * 3 + (f)], acc[mi][f], 0, 0, 0)

#define PAIR(bfC, m0)                                                         \
    MF(bfC, m0, 0, 0); MF(bfC, m0, 0, 1); MF(bfC, m0, 0, 2);                  \
    MF(bfC, (m0)+1, 0, 0); MF(bfC, (m0)+1, 0, 1); MF(bfC, (m0)+1, 0, 2);      \
    MF(bfC, m0, 1, 0); MF(bfC, m0, 1, 1); MF(bfC, m0, 1, 2);                  \
    MF(bfC, (m0)+1, 1, 0); MF(bfC, (m0)+1, 1, 1); MF(bfC, (m0)+1, 1, 2);      \
    MF(bfC, m0, 2, 0); MF(bfC, m0, 2, 1); MF(bfC, m0, 2, 2);                  \
    MF(bfC, (m0)+1, 2, 0); MF(bfC, (m0)+1, 2, 1); MF(bfC, (m0)+1, 2, 2);

#define PAIR9(bfC)                                                            \
    MF(bfC, 8, 0, 0); MF(bfC, 8, 0, 1); MF(bfC, 8, 0, 2);                     \
    MF(bfC, 8, 1, 0); MF(bfC, 8, 1, 1); MF(bfC, 8, 1, 2);                     \
    MF(bfC, 8, 2, 0); MF(bfC, 8, 2, 1); MF(bfC, 8, 2, 2);

#define LDA_(row) (*(const i32x4*)(xT + (row) * 64 + coffN))
#define LDB_(jh, f) (*(const i32x4*)(Bgb + (tn3 + (jh)) * 3072 + (f) * 1024))

    // Per tloc T: 5 MFMA clusters with next-tloc loads threaded between them.
    // af slot k dies after the cluster containing mi=k -> reload in place.
#define TLOC(T, bfC, bfN) {                                                   \
        const int rbn   = tw + 16 - ((T) + 1) + lrow;   /* next tloc rows  */ \
        const int coffN = ((quad ^ ((rbn >> 1) & 3)) << 4);                   \
        const int tn3   = (((T) + 1) & 15) * 3;         /* clamped: t=16->0 */\
        __builtin_amdgcn_s_setprio(1);                                        \
        PAIR(bfC, 0)                                                          \
        af[0] = LDA_(rbn);        af[1] = LDA_(rbn + 16);                     \
        bfN[0] = LDB_(0, 0); bfN[1] = LDB_(0, 1); bfN[2] = LDB_(0, 2);        \
        PAIR(bfC, 2)                                                          \
        af[2] = LDA_(rbn + 32);   af[3] = LDA_(rbn + 48);                     \
        bfN[3] = LDB_(1, 0); bfN[4] = LDB_(1, 1); bfN[5] = LDB_(1, 2);        \
        PAIR(bfC, 4)                                                          \
        af[4] = LDA_(rbn + 64);   af[5] = LDA_(rbn + 80);                     \
        bfN[6] = LDB_(2, 0); bfN[7] = LDB_(2, 1); bfN[8] = LDB_(2, 2);        \
        PAIR(bfC, 6)                                                          \
        af[6] = LDA_(rbn + 96);   af[7] = LDA_(rbn + 112);                    \
        PAIR9(bfC)                                                            \
        af[8] = LDA_(rbn + 128);  af[9] = LDA_(rbn + 144);                    \
        af[10] = LDA_(rbn + 160);                                             \
        __builtin_amdgcn_s_setprio(0);                                        \
    }

    for (int tp = 0; tp < 8; ++tp) {
        TLOC(2 * tp,     bfA, bfB)
        TLOC(2 * tp + 1, bfB, bfA)
        // t=15's "next" loads hit valid rows (<=623) / wrapped t=0 B-frags;
        // values are never consumed.
    }

#undef MF
#undef PAIR
#undef PAIR9
#undef LDA_
#undef LDB_
#undef TLOC

    // epilogue: C/D col=lane&15 (ol), row=quad*4+r (t); digits in-lane
    const size_t potb = (size_t)b * TP_;
#pragma unroll
    for (int mi = 0; mi < 9; ++mi) {
#pragma unroll
        for (int r = 0; r < 4; ++r) {
            int t = tw + mi * 16 + quad * 4 + r;
            if (t < TP_) {
                double pq = ((double)acc[mi][0][r]
                           + 256.0   * (double)acc[mi][1][r]
                           + 65536.0 * (double)acc[mi][2][r])
                          * (1.0 / 4194304.0);
                pot[(potb + t) * O_ + oc * 16 + lrow] = (float)pq;
            }
        }
    }
}

// ===========================================================================
// scan_fused: memset + scan_prep + scan_run in ONE kernel.
// block = (nc, b): SCH=16 neurons x 1024 threads.
//  P1: argmax/threshold from pot -> codeW[nl][t] in LDS (bit-identical
//      decisions to the reference scan).
//  P2: ballot-based depression walk — wave w owns neuron w; 64-lane window,
//      __ballot + ctz finds the first spike, uniform advance >= 48.
//      Decision-identical to the serial reference walk.  (Validated on
//      hardware in round 4: passed with absmax 0.0.)
//  P3: all threads densely write the 10x16x561 output tile.
// ===========================================================================
__global__ __launch_bounds__(1024) void scan_fused(
    const float* __restrict__ pot,    // [B_*TP_][O_]
    float* __restrict__ out)          // [B_][OC_][N_][TP_]
{
    __shared__ unsigned char codeW[SCH * CPITCH];   // [nl][t]
    __shared__ unsigned char ocW[SCH * CPITCH];

    const int tid = threadIdx.x;
    const int nc = blockIdx.x;        // 0..15 (neuron chunk of 16)
    const int b  = blockIdx.y;        // 0..15
    const int n0 = nc * SCH;

    // P1: per (t, nl) argmax over 10 channels + threshold
    for (int pair = tid; pair < TP_ * SCH; pair += 1024) {
        int t = pair >> 4, nl = pair & 15;
        const float* p = pot + ((size_t)(b * TP_ + t)) * O_ + n0 + nl;
        float best = p[0]; int bo = 0;
#pragma unroll
        for (int ch = 1; ch < OC_; ++ch) {
            float v = p[ch * N_];
            if (v > best) { best = v; bo = ch; }   // strict >: FIRST max wins
        }
        codeW[nl * CPITCH + t] =
            ((best + 16.0f) > 32.0f) ? (unsigned char)(bo + 1) : (unsigned char)0;
        ocW[nl * CPITCH + t] = 0;
    }
    __syncthreads();

    // P2: ballot depression walk — wave w = neuron w, all 64 lanes scan
    {
        const int wv = tid >> 6;          // 0..15 == nl
        const int ln = tid & 63;
        const unsigned char* c = &codeW[wv * CPITCH];
        unsigned char* o = &ocW[wv * CPITCH];
        int t = 0;
        while (t < TP_) {
            int tt = t + ln;
            unsigned char v = (tt < TP_) ? c[tt] : (unsigned char)0;
            unsigned long long mask = __ballot(v != 0);
            if (mask == 0ULL) { t += 64; continue; }
            int k = (int)__builtin_ctzll(mask);
            if (ln == k) o[t + k] = v;    // lane k holds the winner code
            t += k + KS_;
        }
    }
    __syncthreads();

    // P3: dense output write: out[b][ch][n0+nl][t]
    float* ob = out + (((size_t)b * OC_) * N_ + n0) * TP_;
    for (int idx = tid; idx < OC_ * SCH * TP_; idx += 1024) {
        int r = idx / TP_;            // r = ch*16 + nl
        int t = idx - r * TP_;
        int ch = r >> 4, nl = r & 15;
        float v = (ocW[nl * CPITCH + t] == (unsigned char)(ch + 1)) ? 1.0f : 0.0f;
        ob[((size_t)ch * N_ + nl) * TP_ + t] = v;
    }
}

// ===========================================================================
// FALLBACK (round-1 direct conv) — only if ws_size too small
// ===========================================================================
__global__ void transpose_w(const float* __restrict__ w, float* __restrict__ wT) {
    int idx = blockIdx.x * 256 + threadIdx.x;
    if (idx >= O_ * S_) return;
    int o = idx >> 6, i = idx & 63;
    wT[i * O_ + o] = w[idx];
}

__global__ __launch_bounds__(256) void conv_kernel(
    const float* __restrict__ x, const float* __restrict__ wT,
    float* __restrict__ pot)
{
    const int b  = blockIdx.y;
    const int t0 = blockIdx.z * TT;
    const int o  = blockIdx.x * 256 + threadIdx.x;

    __shared__ __align__(16) float xsh[S_][WROW];
    for (int idx = threadIdx.x; idx < S_ * WROW; idx += 256) {
        int i = idx / WROW, m = idx - i * WROW;
        int t = t0 - KS_ + m;
        float v = 0.0f;
        if (t >= 0 && t < T_) v = x[(b * S_ + i) * T_ + t];
        xsh[i][m] = v;
    }
    __syncthreads();

    float acch[TT], accl[TT];
#pragma unroll
    for (int tl = 0; tl < TT; ++tl) { acch[tl] = 0.0f; accl[tl] = 0.0f; }

    for (int i = 0; i < S_; ++i) {
        float xw[WROW];
#pragma unroll
        for (int w4 = 0; w4 < WROW / 4; ++w4) {
            const float4 v = *reinterpret_cast<const float4*>(&xsh[i][w4 * 4]);
            xw[w4 * 4 + 0] = v.x; xw[w4 * 4 + 1] = v.y;
            xw[w4 * 4 + 2] = v.z; xw[w4 * 4 + 3] = v.w;
        }
        const float wv = wT[i * O_ + o];
#pragma unroll
        for (int j = 1; j < KS_; ++j) {
            float rise = (float)j * 0.0625f;
            float leak = -((float)j - wv * 16.0f) * 0.03125f + wv;
            float kv   = fmaxf(0.0f, fminf(rise, leak));
            float khi  = rintf(kv * 4096.0f) * 2.44140625e-4f;
            float klo  = kv - khi;
#pragma unroll
            for (int tl = 0; tl < TT; ++tl) {
                float xv = xw[tl + (KS_ - 1) - j];
                acch[tl] = fmaf(xv, khi, acch[tl]);
                accl[tl] = fmaf(xv, klo, accl[tl]);
            }
        }
    }
#pragma unroll
    for (int tl = 0; tl < TT; ++tl) {
        int t = t0 + tl;
        if (t < TP_) pot[((size_t)b * TP_ + t) * O_ + o] = acch[tl] + accl[tl];
    }
}

__global__ void scan_prep(const float* __restrict__ pot, unsigned char* __restrict__ code) {
    int idx = blockIdx.x * 256 + threadIdx.x;
    if (idx >= B_ * TP_ * N_) return;
    int n  = idx & (N_ - 1);
    int bt = idx >> 8;
    const float* p = pot + (size_t)bt * O_ + n;
    float best = p[0]; int bo = 0;
#pragma unroll
    for (int oc = 1; oc < OC_; ++oc) {
        float v = p[oc * N_];
        if (v > best) { best = v; bo = oc; }
    }
    code[idx] = ((best + 16.0f) > 32.0f) ? (unsigned char)(bo + 1) : (unsigned char)0;
}

__global__ void scan_run(const unsigned char* __restrict__ code, float* __restrict__ out) {
    int idx = blockIdx.x * 256 + threadIdx.x;
    if (idx >= B_ * N_) return;
    int b = idx >> 8, n = idx & 255;
    const unsigned char* c = code + (size_t)b * TP_ * N_ + n;
    int t = 0;
    while (t < TP_) {
        unsigned char buf[KS_];
#pragma unroll
        for (int k = 0; k < KS_; ++k) {
            int tt = t + k;
            buf[k] = (tt < TP_) ? c[(size_t)tt * N_] : (unsigned char)0;
        }
        int adv = KS_;
#pragma unroll
        for (int k = 0; k < KS_; ++k) {
            if (buf[k]) {
                out[(((size_t)b * OC_ + (buf[k] - 1)) * N_ + n) * TP_ + (t + k)] = 1.0f;
                adv = k + KS_;
                break;
            }
        }
        t += adv;
    }
}

// ===========================================================================
extern "C" void kernel_launch(void* const* d_in, const int* in_sizes, int n_in,
                              void* d_out, int out_size, void* d_ws, size_t ws_size,
                              hipStream_t stream) {
    const float* x = (const float*)d_in[0];   // [16][1][64][512] binary
    const float* w = (const float*)d_in[1];   // [2560][64]
    float* out = (float*)d_out;               // [16][10][256][561]

    char* ws = (char*)d_ws;
    const size_t szX = (size_t)B_ * T_ * S_;                    //     524,288
    const size_t szB = (size_t)NOC * KS_ * 48 * 64;             //  23,592,960
    const size_t szP = (size_t)B_ * TP_ * O_ * 4;               //  91,914,240
    const size_t szC = (size_t)B_ * TP_ * N_;                   //   2,297,856
    const size_t need = szX + szB + szP + szC;                  // ~118.3 MB

    if (ws_size >= need) {
        unsigned char* xb  = (unsigned char*)ws;
        signed char* Bg    = (signed char*)(ws + szX);
        float* pot         = (float*)(ws + szX + szB);

        prep_all<<<2432, 256, 0, stream>>>(x, w, xb, Bg);
        gemm_i8<<<dim3(NOC, B_), 256, 0, stream>>>(xb, Bg, pot);
        scan_fused<<<dim3(N_ / SCH, B_), 1024, 0, stream>>>(pot, out);
    } else {
        // fallback: round-1 direct conv (needs ~95 MB)
        size_t pot_bytes  = (size_t)B_ * TP_ * O_ * sizeof(float);
        size_t code_bytes = (size_t)B_ * TP_ * N_;
        float* pot = (float*)ws;
        unsigned char* code = (unsigned char*)(ws + pot_bytes);
        float* wT = (float*)(ws + pot_bytes + code_bytes);

        hipMemsetAsync(d_out, 0, (size_t)out_size * sizeof(float), stream);
        transpose_w<<<(O_ * S_ + 255) / 256, 256, 0, stream>>>(w, wT);
        conv_kernel<<<dim3(O_ / 256, B_, (TP_ + TT - 1) / TT), 256, 0, stream>>>(x, wT, pot);
        scan_prep<<<(B_ * TP_ * N_ + 255) / 256, 256, 0, stream>>>(pot, code);
        scan_run<<<(B_ * N_ + 255) / 256, 256, 0, stream>>>(code, out);
    }
}

// Round 7
// 237.094 us; speedup vs baseline: 1.2113x; 1.0335x over previous
//
#include <hip/hip_runtime.h>

// Problem constants (from reference)
#define B_   16
#define OC_  10
#define N_   256
#define O_   2560   // OC_*N_
#define S_   64     // synapses
#define T_   512
#define KS_  48
#define TP_  561    // T + KS + 1
#define TT   24     // (fallback conv) time steps per thread
#define WROW 72     // (fallback conv) LDS row stride

// GEMM constants
#define XROWS 624           // xT rows: t' + 48 - j range, zero-padded
#define SCH    16           // neurons per block = one 64-B line
#define CPITCH 572          // scan LDS row pitch (143 dwords, gcd(143,32)=1)

using i32x4 = __attribute__((ext_vector_type(4))) int;

// ===========================================================================
// prep_all: one dispatch, grid-strided.
//  - blocks [0, 512):    x [16][64][512] f32 -> xb [16][512][64] {0,1}  (x4)
//  - blocks [512, 2432): taps -> three signed base-256 digits (22-bit fixed
//    point) into Bg[oc][pos][row=d*16+ol][64], pos = 3*jm + jh  (x16)
// ===========================================================================
__global__ void prep_all(const float* __restrict__ x, const float* __restrict__ w,
                         unsigned char* __restrict__ xb, signed char* __restrict__ Bg) {
    if (blockIdx.x < 512) {
#pragma unroll
        for (int it = 0; it < 4; ++it) {
            int idx = blockIdx.x * 256 + threadIdx.x + it * 131072;  // < 524288
            int t = idx & 511;
            int bi = idx >> 9;
            int i = bi & 63, b = bi >> 6;
            xb[((size_t)(b * 512 + t) << 6) + i] = (x[idx] != 0.0f) ? 1 : 0;
        }
    } else {
        int base = (blockIdx.x - 512) * 256 + threadIdx.x;
#pragma unroll
        for (int it = 0; it < 16; ++it) {
            int idx = base + it * 491520;                  // < 7,864,320 exactly
            int i = idx & 63;
            int oj = idx >> 6;
            int j = oj % KS_, o = oj / KS_;
            float wv = w[(o << 6) + i];
            float rise = (float)j * 0.0625f;
            float leak = -((float)j - wv * 16.0f) * 0.03125f + wv;
            float kv   = fmaxf(0.0f, fminf(rise, leak));     // in [0,1]
            int q  = (int)lrintf(kv * 4194304.0f);           // kv * 2^22
            int d0 = ((q + 128) & 255) - 128;                // [-128,127]
            int q1 = (q - d0) >> 8;
            int d1 = ((q1 + 128) & 255) - 128;               // [-128,127]
            int d2 = (q1 - d1) >> 8;                         // [0,64]
            int oc = o >> 4, ol = o & 15;
            int jm = j & 15, jh = j >> 4;
            int pos = jm * 3 + jh;                           // triple-grouped
            size_t bse = (((size_t)(oc * KS_ + pos) * 48) + ol) * 64 + i;
            Bg[bse]            = (signed char)d0;            // digit 0
            Bg[bse + 16 * 64]  = (signed char)d1;            // digit 1
            Bg[bse + 32 * 64]  = (signed char)d2;            // digit 2
        }
    }
}

// ===========================================================================
// gemm_scan (r17): FULL FUSION — pot never touches HBM.
// Round-6 analysis: gemm at 91% of the 16x16-i8 ubench floor; the remaining
// 124 us residual is dominated by the pot round-trip (91.9 MB write in gemm
// + 91.9 MB read in scan) and the extra kernel.  Fix: block = (nc, b) — the
// SCAN's partition — with 8 waves = (t-quarter x channel-half).  Each wave
// runs the PROVEN r14 K-loop tiling (144t x 16o, acc 108, af-roll pipeline,
// 2 waves/SIMD) five times (channel loop), doing a running argmax into a
// per-half LDS buffer after each channel.  Then: merge halves -> code ->
// ballot depression walk -> dense out write, all in one kernel.
//  - MFMA count, per-wave regs, waves/SIMD identical to the proven config.
//  - Decision arithmetic copied verbatim: same double digit-combine -> f32,
//    strict-> ascending-channel argmax (first max wins; half-0 preferred on
//    cross-half ties), (best + 16.0f) > 32.0f threshold.
//  - LDS: xT 39,936 + keyB 73,728 + codeB 18,432 + codeW/ocW 18,304
//    = 150,400 B -> 1 block/CU, 8 waves = 2/SIMD (same occupancy as r14).
// ===========================================================================
__global__ __launch_bounds__(512, 2) void gemm_scan(
    const unsigned char* __restrict__ xb,   // [16][512][64]
    const signed char*  __restrict__ Bg,    // [160][48][48][64]
    float* __restrict__ out)                // [B_][OC_][N_][TP_]
{
    __shared__ __align__(16) unsigned char xT[XROWS * 64];      // 39,936
    __shared__ float         keyB[2][576 * 16];                 // 73,728
    __shared__ unsigned char codeB[2][576 * 16];                // 18,432
    __shared__ unsigned char codeW[SCH * CPITCH];               //  9,152
    __shared__ unsigned char ocW[SCH * CPITCH];                 //  9,152

    const int tid  = threadIdx.x;
    const int lane = tid & 63;
    const int wave = tid >> 6;          // 0..7
    const int tq   = wave >> 1;         // t-quarter 0..3
    const int chh  = wave & 1;          // channel half 0..1
    const int nc = blockIdx.x;          // 0..15 neuron chunk
    const int b  = blockIdx.y;          // 0..15
    const int lrow = lane & 15;
    const int quad = lane >> 4;
    const int tw = tq * 144;            // wave m-base (t)

    const size_t SL = (size_t)KS_ * 48 * 64;     // 147,456 B per oc-slice
    // first channel of this half: ch = chh*5 -> oc = ch*16 + nc
    const signed char* Bcur = Bg + (size_t)(chh * 80 + nc) * SL
                            + lrow * 64 + quad * 16;

    // xT fill: zero ONLY pad rows (0..48, 561..623); data rows 49..560 <- x[b]
    for (int z = tid; z < 112 * 4; z += 512) {
        int zi = z >> 2, p = z & 3;
        int r = (zi < 49) ? zi : (561 + zi - 49);
        *(i32x4*)(xT + r * 64 + p * 16) = (i32x4){0, 0, 0, 0};
    }
    const unsigned char* xbb = xb + ((size_t)b << 15);   // 512*64 bytes
    for (int q = tid; q < 2048; q += 512) {              // 16-B chunks
        i32x4 v = *(const i32x4*)(xbb + q * 16);
        int t = q >> 2, p = q & 3;
        int r = 49 + t;
        *(i32x4*)(xT + r * 64 + ((p ^ ((r >> 1) & 3)) << 4)) = v;
    }

    i32x4 acc[9][3];
    i32x4 af[11], bfA[9], bfB[9];

    // B(ch-first, t=0) prefetch issued before the barrier (no xT dependency)
#pragma unroll
    for (int jh = 0; jh < 3; ++jh)
#pragma unroll
        for (int f = 0; f < 3; ++f)
            bfA[jh * 3 + f] = *(const i32x4*)(Bcur + jh * 3072 + f * 1024);

    __syncthreads();   // xT ready

    // af prologue for t=0
    {
        const int rb0 = tw + 16 + lrow;
        const int ca0 = ((quad ^ ((rb0 >> 1) & 3)) << 4);
#pragma unroll
        for (int k = 0; k < 11; ++k)
            af[k] = *(const i32x4*)(xT + (rb0 + k * 16) * 64 + ca0);
    }

#define MF(bfC, mi, jh, f)                                                    \
    acc[mi][f] = __builtin_amdgcn_mfma_i32_16x16x64_i8(                       \
        af[(mi) + 2 - (jh)], bfC[(jh) * 3 + (f)], acc[mi][f], 0, 0, 0)

#define PAIR(bfC, m0)                                                         \
    MF(bfC, m0, 0, 0); MF(bfC, m0, 0, 1); MF(bfC, m0, 0, 2);                  \
    MF(bfC, (m0)+1, 0, 0); MF(bfC, (m0)+1, 0, 1); MF(bfC, (m0)+1, 0, 2);      \
    MF(bfC, m0, 1, 0); MF(bfC, m0, 1, 1); MF(bfC, m0, 1, 2);                  \
    MF(bfC, (m0)+1, 1, 0); MF(bfC, (m0)+1, 1, 1); MF(bfC, (m0)+1, 1, 2);      \
    MF(bfC, m0, 2, 0); MF(bfC, m0, 2, 1); MF(bfC, m0, 2, 2);                  \
    MF(bfC, (m0)+1, 2, 0); MF(bfC, (m0)+1, 2, 1); MF(bfC, (m0)+1, 2, 2);

#define PAIR9(bfC)                                                            \
    MF(bfC, 8, 0, 0); MF(bfC, 8, 0, 1); MF(bfC, 8, 0, 2);                     \
    MF(bfC, 8, 1, 0); MF(bfC, 8, 1, 1); MF(bfC, 8, 1, 2);                     \
    MF(bfC, 8, 2, 0); MF(bfC, 8, 2, 1); MF(bfC, 8, 2, 2);

#define LDA_(row) (*(const i32x4*)(xT + (row) * 64 + coffN))
#define LDB_(BP, jh, f) (*(const i32x4*)((BP) + (tn3 + (jh)) * 3072 + (f) * 1024))

    // Per tloc T: 5 MFMA clusters, next-tloc loads threaded between them.
    // BP = B base for the wrapped (t+1) prefetch (next channel at T==15).
#define TLOC(T, bfC, bfN, BP) {                                               \
        const int rbn   = tw + 16 - (((T) + 1) & 15) + lrow;                  \
        const int coffN = ((quad ^ ((rbn >> 1) & 3)) << 4);                   \
        const int tn3   = (((T) + 1) & 15) * 3;                               \
        __builtin_amdgcn_s_setprio(1);                                        \
        PAIR(bfC, 0)                                                          \
        af[0] = LDA_(rbn);        af[1] = LDA_(rbn + 16);                     \
        bfN[0] = LDB_(BP, 0, 0); bfN[1] = LDB_(BP, 0, 1); bfN[2] = LDB_(BP, 0, 2); \
        PAIR(bfC, 2)                                                          \
        af[2] = LDA_(rbn + 32);   af[3] = LDA_(rbn + 48);                     \
        bfN[3] = LDB_(BP, 1, 0); bfN[4] = LDB_(BP, 1, 1); bfN[5] = LDB_(BP, 1, 2); \
        PAIR(bfC, 4)                                                          \
        af[4] = LDA_(rbn + 64);   af[5] = LDA_(rbn + 80);                     \
        bfN[6] = LDB_(BP, 2, 0); bfN[7] = LDB_(BP, 2, 1); bfN[8] = LDB_(BP, 2, 2); \
        PAIR(bfC, 6)                                                          \
        af[6] = LDA_(rbn + 96);   af[7] = LDA_(rbn + 112);                    \
        PAIR9(bfC)                                                            \
        af[8] = LDA_(rbn + 128);  af[9] = LDA_(rbn + 144);                    \
        af[10] = LDA_(rbn + 160);                                             \
        __builtin_amdgcn_s_setprio(0);                                        \
    }

    for (int c = 0; c < 5; ++c) {
        // clamp next base at c==4 (dummy prefetch values, never consumed;
        // keeps all reads inside Bg)
        const signed char* Bnxt = (c == 4) ? Bcur : (Bcur + 16 * SL);

#pragma unroll
        for (int mi = 0; mi < 9; ++mi)
#pragma unroll
            for (int f = 0; f < 3; ++f)
                acc[mi][f] = (i32x4){0, 0, 0, 0};

        for (int tp = 0; tp < 7; ++tp) {
            TLOC(2 * tp,     bfA, bfB, Bcur)
            TLOC(2 * tp + 1, bfB, bfA, Bcur)
        }
        TLOC(14, bfA, bfB, Bcur)
        TLOC(15, bfB, bfA, Bnxt)    // prefetch next channel's t=0 into bfA;
                                    // af wraps to t=0 rows (ch-independent)

        // per-channel epilogue: digits -> f32 pot (verbatim decision math),
        // running argmax into this half's LDS buffer (element owned by
        // exactly one wave -> race-free).
        {
            const unsigned char cv = (unsigned char)(chh * 5 + c + 1);
            const int cc = c;
#pragma unroll
            for (int mi = 0; mi < 9; ++mi) {
#pragma unroll
                for (int r = 0; r < 4; ++r) {
                    int t = tw + mi * 16 + quad * 4 + r;     // < 576
                    float pq = (float)(((double)acc[mi][0][r]
                               + 256.0   * (double)acc[mi][1][r]
                               + 65536.0 * (double)acc[mi][2][r])
                              * (1.0 / 4194304.0));
                    int ix = t * 16 + lrow;
                    if (cc == 0) {
                        keyB[chh][ix] = pq; codeB[chh][ix] = cv;
                    } else if (pq > keyB[chh][ix]) {         // strict >: first max wins
                        keyB[chh][ix] = pq; codeB[chh][ix] = cv;
                    }
                }
            }
        }
        Bcur = Bnxt;
    }

#undef MF
#undef PAIR
#undef PAIR9
#undef LDA_
#undef LDB_
#undef TLOC

    __syncthreads();   // all halves' argmax buffers complete

    // merge halves -> codeW[nl][t]; half 0 preferred on ties (lower channel)
    for (int ix = tid; ix < 576 * 16; ix += 512) {
        int t = ix >> 4, nl = ix & 15;
        if (t >= TP_) continue;
        float f0 = keyB[0][ix];
        float f1 = keyB[1][ix];
        float best = f0;
        unsigned char cd = codeB[0][ix];
        if (f1 > f0) { best = f1; cd = codeB[1][ix]; }
        codeW[nl * CPITCH + t] = ((best + 16.0f) > 32.0f) ? cd : (unsigned char)0;
        ocW[nl * CPITCH + t] = 0;
    }
    __syncthreads();

    // ballot depression walk — wave handles neurons {wave, wave+8}
    {
        const int ln = tid & 63;
        for (int nsel = wave; nsel < SCH; nsel += 8) {
            const unsigned char* cp = &codeW[nsel * CPITCH];
            unsigned char* op = &ocW[nsel * CPITCH];
            int t = 0;
            while (t < TP_) {
                int tt = t + ln;
                unsigned char v = (tt < TP_) ? cp[tt] : (unsigned char)0;
                unsigned long long mask = __ballot(v != 0);
                if (mask == 0ULL) { t += 64; continue; }
                int k = (int)__builtin_ctzll(mask);
                if (ln == k) op[t + k] = v;
                t += k + KS_;
            }
        }
    }
    __syncthreads();

    // dense output write: out[b][ch][n0+nl][t]
    float* ob = out + (((size_t)b * OC_) * N_ + nc * SCH) * TP_;
    for (int idx = tid; idx < OC_ * SCH * TP_; idx += 512) {
        int r = idx / TP_;            // r = ch*16 + nl
        int t = idx - r * TP_;
        int ch = r >> 4, nl = r & 15;
        float v = (ocW[nl * CPITCH + t] == (unsigned char)(ch + 1)) ? 1.0f : 0.0f;
        ob[((size_t)ch * N_ + nl) * TP_ + t] = v;
    }
}

// ===========================================================================
// FALLBACK (round-1 direct conv) — only if ws_size too small
// ===========================================================================
__global__ void transpose_w(const float* __restrict__ w, float* __restrict__ wT) {
    int idx = blockIdx.x * 256 + threadIdx.x;
    if (idx >= O_ * S_) return;
    int o = idx >> 6, i = idx & 63;
    wT[i * O_ + o] = w[idx];
}

__global__ __launch_bounds__(256) void conv_kernel(
    const float* __restrict__ x, const float* __restrict__ wT,
    float* __restrict__ pot)
{
    const int b  = blockIdx.y;
    const int t0 = blockIdx.z * TT;
    const int o  = blockIdx.x * 256 + threadIdx.x;

    __shared__ __align__(16) float xsh[S_][WROW];
    for (int idx = threadIdx.x; idx < S_ * WROW; idx += 256) {
        int i = idx / WROW, m = idx - i * WROW;
        int t = t0 - KS_ + m;
        float v = 0.0f;
        if (t >= 0 && t < T_) v = x[(b * S_ + i) * T_ + t];
        xsh[i][m] = v;
    }
    __syncthreads();

    float acch[TT], accl[TT];
#pragma unroll
    for (int tl = 0; tl < TT; ++tl) { acch[tl] = 0.0f; accl[tl] = 0.0f; }

    for (int i = 0; i < S_; ++i) {
        float xw[WROW];
#pragma unroll
        for (int w4 = 0; w4 < WROW / 4; ++w4) {
            const float4 v = *reinterpret_cast<const float4*>(&xsh[i][w4 * 4]);
            xw[w4 * 4 + 0] = v.x; xw[w4 * 4 + 1] = v.y;
            xw[w4 * 4 + 2] = v.z; xw[w4 * 4 + 3] = v.w;
        }
        const float wv = wT[i * O_ + o];
#pragma unroll
        for (int j = 1; j < KS_; ++j) {
            float rise = (float)j * 0.0625f;
            float leak = -((float)j - wv * 16.0f) * 0.03125f + wv;
            float kv   = fmaxf(0.0f, fminf(rise, leak));
            float khi  = rintf(kv * 4096.0f) * 2.44140625e-4f;
            float klo  = kv - khi;
#pragma unroll
            for (int tl = 0; tl < TT; ++tl) {
                float xv = xw[tl + (KS_ - 1) - j];
                acch[tl] = fmaf(xv, khi, acch[tl]);
                accl[tl] = fmaf(xv, klo, accl[tl]);
            }
        }
    }
#pragma unroll
    for (int tl = 0; tl < TT; ++tl) {
        int t = t0 + tl;
        if (t < TP_) pot[((size_t)b * TP_ + t) * O_ + o] = acch[tl] + accl[tl];
    }
}

__global__ void scan_prep(const float* __restrict__ pot, unsigned char* __restrict__ code) {
    int idx = blockIdx.x * 256 + threadIdx.x;
    if (idx >= B_ * TP_ * N_) return;
    int n  = idx & (N_ - 1);
    int bt = idx >> 8;
    const float* p = pot + (size_t)bt * O_ + n;
    float best = p[0]; int bo = 0;
#pragma unroll
    for (int oc = 1; oc < OC_; ++oc) {
        float v = p[oc * N_];
        if (v > best) { best = v; bo = oc; }
    }
    code[idx] = ((best + 16.0f) > 32.0f) ? (unsigned char)(bo + 1) : (unsigned char)0;
}

__global__ void scan_run(const unsigned char* __restrict__ code, float* __restrict__ out) {
    int idx = blockIdx.x * 256 + threadIdx.x;
    if (idx >= B_ * N_) return;
    int b = idx >> 8, n = idx & 255;
    const unsigned char* c = code + (size_t)b * TP_ * N_ + n;
    int t = 0;
    while (t < TP_) {
        unsigned char buf[KS_];
#pragma unroll
        for (int k = 0; k < KS_; ++k) {
            int tt = t + k;
            buf[k] = (tt < TP_) ? c[(size_t)tt * N_] : (unsigned char)0;
        }
        int adv = KS_;
#pragma unroll
        for (int k = 0; k < KS_; ++k) {
            if (buf[k]) {
                out[(((size_t)b * OC_ + (buf[k] - 1)) * N_ + n) * TP_ + (t + k)] = 1.0f;
                adv = k + KS_;
                break;
            }
        }
        t += adv;
    }
}

// ===========================================================================
extern "C" void kernel_launch(void* const* d_in, const int* in_sizes, int n_in,
                              void* d_out, int out_size, void* d_ws, size_t ws_size,
                              hipStream_t stream) {
    const float* x = (const float*)d_in[0];   // [16][1][64][512] binary
    const float* w = (const float*)d_in[1];   // [2560][64]
    float* out = (float*)d_out;               // [16][10][256][561]

    char* ws = (char*)d_ws;
    const size_t szX = (size_t)B_ * T_ * S_;                    //     524,288
    const size_t szB = (size_t)160 * KS_ * 48 * 64;             //  23,592,960
    const size_t need = szX + szB;                              //  ~24.1 MB

    if (ws_size >= need) {
        unsigned char* xb  = (unsigned char*)ws;
        signed char* Bg    = (signed char*)(ws + szX);

        prep_all<<<2432, 256, 0, stream>>>(x, w, xb, Bg);
        gemm_scan<<<dim3(16, 16), 512, 0, stream>>>(xb, Bg, out);
    } else {
        // fallback: round-1 direct conv (needs ~95 MB)
        size_t pot_bytes  = (size_t)B_ * TP_ * O_ * sizeof(float);
        size_t code_bytes = (size_t)B_ * TP_ * N_;
        float* pot = (float*)ws;
        unsigned char* code = (unsigned char*)(ws + pot_bytes);
        float* wT = (float*)(ws + pot_bytes + code_bytes);

        hipMemsetAsync(d_out, 0, (size_t)out_size * sizeof(float), stream);
        transpose_w<<<(O_ * S_ + 255) / 256, 256, 0, stream>>>(w, wT);
        conv_kernel<<<dim3(O_ / 256, B_, (TP_ + TT - 1) / TT), 256, 0, stream>>>(x, wT, pot);
        scan_prep<<<(B_ * TP_ * N_ + 255) / 256, 256, 0, stream>>>(pot, code);
        scan_run<<<(B_ * N_ + 255) / 256, 256, 0, stream>>>(code, out);
    }
}